// Round 2
// baseline (245.782 us; speedup 1.0000x reference)
//
#include <hip/hip_runtime.h>
#include <hip/hip_bf16.h>

#define N_IN  128
#define N_OUT 64
#define CFB    256          // nodes per coarse bucket (sort granularity)
#define MAXNBC 200          // >= ceil(50000/256) = 196
#define SLACKC 5120         // slots per coarse bucket (mean 4096, +16 sigma)
#define CHUNK  2048         // edges per fill part (391 parts)
#define PADR   136          // LDS row pitch in bf16 (+8 pad -> 2-way banks, free)

typedef __attribute__((ext_vector_type(8))) short short8;
typedef __attribute__((ext_vector_type(4))) float floatx4;
typedef __attribute__((ext_vector_type(2))) float floatx2;

__device__ __forceinline__ unsigned pack_bf16(float a, float b) {
    __hip_bfloat16 ba = __float2bfloat16(a);
    __hip_bfloat16 bb = __float2bfloat16(b);
    unsigned short ua = *(unsigned short*)&ba;
    unsigned short ub = *(unsigned short*)&bb;
    return ((unsigned)ub << 16) | ua;
}
__device__ __forceinline__ float bf16_to_f32(unsigned short u) {
    unsigned v = ((unsigned)u) << 16;
    return *(float*)&v;
}

// Dispatch 1: fold weights into CT[128][128] bf16 (rows 0..63 = out cols,
// 64..127 = z cols) and zero gcur/fdone for this launch iteration.
__global__ __launch_bounds__(256) void prep_kernel(const float* __restrict__ W0,
                                                   const float* __restrict__ W1,
                                                   const float* __restrict__ W2,
                                                   const float* __restrict__ Wfc,
                                                   __hip_bfloat16* __restrict__ CT,
                                                   int* __restrict__ gcur,
                                                   int* __restrict__ fdone,
                                                   int NBC) {
    if (blockIdx.x == 0) {
        for (int i = threadIdx.x; i < NBC; i += 256) gcur[i] = 0;
        if (threadIdx.x == 0) *fdone = 0;
    }
    int t = blockIdx.x * 256 + threadIdx.x;   // 0..16383
    int n = t >> 7;
    int i = t & 127;
    float a = 0.f;
    if (n < 64) {
        #pragma unroll 4
        for (int k = 0; k < 128; ++k)
            a += Wfc[n * 384 + k] * W0[k * N_IN + i];
    } else {
        int o = n - 64;
        #pragma unroll 4
        for (int k = 0; k < 128; ++k)
            a += Wfc[o * 384 + 128 + k] * W1[k * N_IN + i]
               + Wfc[o * 384 + 256 + k] * W2[k * N_IN + i];
    }
    CT[t] = __float2bfloat16(a);
}

// Dispatch 2: fused fill + sort + gemm.
//  blocks < NFB        : scatter one 2048-edge chunk into per-bucket slack
//                        regions, then arrive on fdone (release, agent scope).
//  blocks < NBC (196)  : spin until all NFB fill parts arrived (acquire),
//                        then counting-sort their coarse bucket -> srow/offs/
//                        cnt/dis.  These are the only waiters; every other
//                        block runs to completion, so residency pressure can
//                        never deadlock the spin.
//  blocks >= NBC       : MFMA gemm tile (independent of fill/sort; CT comes
//                        from dispatch 1): out = x@C0^T, z16 = bf16(x@C12^T)
//                        UNSCALED (dis folded in by scale_kernel next).
__global__ __launch_bounds__(256) void fused_kernel(
        const int* __restrict__ ei,
        int* __restrict__ gcur,
        unsigned* __restrict__ gsorted,
        unsigned short* __restrict__ srow,
        int* __restrict__ offs,
        int* __restrict__ cnt,
        float* __restrict__ dis,
        const float* __restrict__ x,
        const __hip_bfloat16* __restrict__ CT,
        float* __restrict__ out,
        __hip_bfloat16* __restrict__ z16,
        int* __restrict__ fdone,
        int E, int N, int NBC, int NFB) {
    __shared__ __align__(16) char smem[(64 + 128) * PADR * 2];   // 52224 B union
    int tid = threadIdx.x;
    int bid = blockIdx.x;

    // ---------------- fill part ----------------
    if (bid < NFB) {
        int* lcnt = (int*)smem;
        int* gbase_s = lcnt + MAXNBC;
        int base = bid * CHUNK;
        for (int i = tid; i < NBC; i += 256) lcnt[i] = 0;
        __syncthreads();
        int myc[CHUNK / 256];
        #pragma unroll
        for (int q = 0; q < CHUNK / 256; ++q) {
            int e = base + q * 256 + tid;
            int c = (e < E) ? ei[E + e] : -1;
            myc[q] = c;
            if (c >= 0) atomicAdd(&lcnt[c >> 8], 1);
        }
        __syncthreads();
        for (int f = tid; f < NBC; f += 256) {
            int n = lcnt[f];
            gbase_s[f] = (n > 0) ? (f * SLACKC + atomicAdd(&gcur[f], n)) : 0;
        }
        __syncthreads();
        #pragma unroll
        for (int q = 0; q < CHUNK / 256; ++q) {
            int c = myc[q];
            if (c >= 0) {
                int e = base + q * 256 + tid;
                unsigned r = (unsigned)ei[e];
                int p = atomicAdd(&gbase_s[c >> 8], 1);
                if (p < ((c >> 8) + 1) * SLACKC)   // overflow guard (P ~ 0)
                    gsorted[p] = ((unsigned)c << 16) | r;
            }
        }
        __threadfence();          // make gsorted/gcur device-visible
        __syncthreads();          // also closes LDS phase before reuse below
        if (tid == 0)
            __hip_atomic_fetch_add(fdone, 1, __ATOMIC_RELEASE,
                                   __HIP_MEMORY_SCOPE_AGENT);
    }

    if (bid < NBC) {
        // ---------------- sort partition ----------------
        if (tid == 0) {
            while (__hip_atomic_load(fdone, __ATOMIC_ACQUIRE,
                                     __HIP_MEMORY_SCOPE_AGENT) < NFB)
                __builtin_amdgcn_s_sleep(2);
        }
        __syncthreads();
        __threadfence();          // acquire for all waves of the block

        unsigned* ev = (unsigned*)smem;               // up to SLACKC edges (20KB)
        int* c256 = (int*)(smem + SLACKC * 4);        // 256 counts
        int* cur  = c256 + 256;                       // 256 cursors
        int* ts   = cur + 256;                        // 256 scan temp
        int f = bid;
        int lo = f * SLACKC;
        int m = min(gcur[f], SLACKC);                 // gcur is relative count
        for (int i = tid; i < m; i += 256) ev[i] = gsorted[lo + i];
        c256[tid] = 0;
        __syncthreads();
        for (int i = tid; i < m; i += 256)
            atomicAdd(&c256[(ev[i] >> 16) & (CFB - 1)], 1);
        __syncthreads();
        int v = c256[tid];
        int xx = v;
        ts[tid] = xx;
        __syncthreads();
        for (int off = 1; off < 256; off <<= 1) {
            int t2 = (tid >= off) ? ts[tid - off] : 0;
            __syncthreads();
            xx += t2; ts[tid] = xx;
            __syncthreads();
        }
        int b = xx - v;          // exclusive prefix
        cur[tid] = b;
        int node = f * CFB + tid;
        if (node < N) {
            offs[node] = lo + b;
            cnt[node] = v;
            dis[node] = v > 0 ? rsqrtf((float)v) : 0.f;
        }
        __syncthreads();
        for (int i = tid; i < m; i += 256) {
            unsigned val = ev[i];
            int cl = (val >> 16) & (CFB - 1);
            int p = atomicAdd(&cur[cl], 1);
            srow[lo + p] = (unsigned short)(val & 0xffffu);
        }
        return;
    }

    // ---------------- gemm partition ----------------
    unsigned short* xs = (unsigned short*)smem;          // 64 x PADR
    unsigned short* Bs = xs + 64 * PADR;                 // 128 x PADR
    int base = (bid - NBC) * 64;

    {   // stage x -> bf16 LDS
        int row = tid >> 2;
        int colq = (tid & 3) * 32;
        int node = base + row;
        unsigned tmp[16];
        if (node < N) {
            const float4* src = (const float4*)(x + (size_t)node * N_IN + colq);
            #pragma unroll
            for (int q = 0; q < 8; ++q) {
                float4 v = src[q];
                tmp[q * 2]     = pack_bf16(v.x, v.y);
                tmp[q * 2 + 1] = pack_bf16(v.z, v.w);
            }
        } else {
            #pragma unroll
            for (int q = 0; q < 16; ++q) tmp[q] = 0u;
        }
        unsigned* dst = (unsigned*)(xs + row * PADR + colq);
        #pragma unroll
        for (int q = 0; q < 16; ++q) dst[q] = tmp[q];
    }
    {   // stage CT -> LDS
        const unsigned* src = (const unsigned*)CT;
        for (int c = tid; c < 8192; c += 256) {
            int row = c >> 6;
            int col = (c & 63) * 2;
            *(unsigned*)(Bs + row * PADR + col) = src[c];
        }
    }
    __syncthreads();

    int wave = tid >> 6, lane = tid & 63;
    int wm = wave & 1, wn = wave >> 1;
    int quad = lane >> 4, l16 = lane & 15;

    floatx4 acc[2][4];
    #pragma unroll
    for (int mt = 0; mt < 2; ++mt)
        #pragma unroll
        for (int nt = 0; nt < 4; ++nt)
            acc[mt][nt] = (floatx4){0.f, 0.f, 0.f, 0.f};

    #pragma unroll
    for (int kc = 0; kc < 4; ++kc) {
        int kof = kc * 32 + quad * 8;
        short8 afr[2], bfr[4];
        #pragma unroll
        for (int mt = 0; mt < 2; ++mt)
            afr[mt] = *(const short8*)(xs + (wm * 32 + mt * 16 + l16) * PADR + kof);
        #pragma unroll
        for (int nt = 0; nt < 4; ++nt)
            bfr[nt] = *(const short8*)(Bs + (wn * 64 + nt * 16 + l16) * PADR + kof);
        #pragma unroll
        for (int mt = 0; mt < 2; ++mt)
            #pragma unroll
            for (int nt = 0; nt < 4; ++nt)
                acc[mt][nt] = __builtin_amdgcn_mfma_f32_16x16x32_bf16(
                    afr[mt], bfr[nt], acc[mt][nt], 0, 0, 0);
    }

    #pragma unroll
    for (int mt = 0; mt < 2; ++mt) {
        #pragma unroll
        for (int reg = 0; reg < 4; ++reg) {
            int node = base + wm * 32 + mt * 16 + quad * 4 + reg;
            if (node >= N) continue;
            if (wn == 0) {
                #pragma unroll
                for (int nt = 0; nt < 4; ++nt)
                    out[(size_t)node * N_OUT + nt * 16 + l16] = acc[mt][nt][reg];
            } else {
                #pragma unroll
                for (int nt = 0; nt < 4; ++nt)
                    z16[((size_t)node << 6) + nt * 16 + l16] =
                        __float2bfloat16(acc[mt][nt][reg]);
            }
        }
    }
}

// Dispatch 3: z8[node][d] = fp8( dis[node] * z16[node][d] ).  Single
// quantization (z16 is bf16), so precision matches the old unscaled-fp8 path.
__global__ __launch_bounds__(256) void scale_kernel(
        const __hip_bfloat16* __restrict__ z16,
        const float* __restrict__ dis,
        unsigned char* __restrict__ z8,
        int N) {
    int t = blockIdx.x * 256 + threadIdx.x;   // one thread = 8 dims
    if (t >= N * 8) return;
    int node = t >> 3;
    float d = dis[node];
    short8 v = *(const short8*)((const unsigned short*)z16 + (size_t)t * 8);
    float f[8];
    #pragma unroll
    for (int j = 0; j < 8; ++j)
        f[j] = bf16_to_f32((unsigned short)v[j]) * d;
    unsigned lo = 0, hi = 0;
    lo = __builtin_amdgcn_cvt_pk_fp8_f32(f[0], f[1], lo, false);
    lo = __builtin_amdgcn_cvt_pk_fp8_f32(f[2], f[3], lo, true);
    hi = __builtin_amdgcn_cvt_pk_fp8_f32(f[4], f[5], hi, false);
    hi = __builtin_amdgcn_cvt_pk_fp8_f32(f[6], f[7], hi, true);
    uint2 o; o.x = lo; o.y = hi;
    *(uint2*)(z8 + (size_t)t * 8) = o;
}

// Dispatch 4: gather.  z8 rows are PRE-SCALED by dis[row], so per-edge work is
// now a single 8B load + adds: no random dis[idx] line-requests, no dv shfl.
__global__ __launch_bounds__(256) void gather_kernel(
        const int* __restrict__ offs, const int* __restrict__ cnt,
        const unsigned short* __restrict__ srow, const unsigned char* __restrict__ z8,
        float* __restrict__ out, int N) {
    int lane = threadIdx.x & 63;
    int quarter = lane >> 4;     // which node of the four
    int ql   = lane & 15;        // lane within quarter
    int sub  = ql >> 3;          // edge slot 0..1
    int jj   = ql & 7;           // byte-chunk: dims 8jj..8jj+7
    int node = blockIdx.x * 16 + (threadIdx.x >> 6) * 4 + quarter;
    int start = 0, deg = 0;
    if (node < N) { start = offs[node]; deg = cnt[node]; }
    float a[8] = {0.f, 0.f, 0.f, 0.f, 0.f, 0.f, 0.f, 0.f};
    for (int k0 = 0; k0 < deg; k0 += 16) {
        int m = min(16, deg - k0);               // per-quarter edge count
        int idx = 0;
        if (ql < m)
            idx = (int)srow[start + k0 + ql];    // coalesced u16, all quarters at once
        #pragma unroll
        for (int it = 0; it < 8; ++it) {
            int s0 = it * 2 + sub;
            int src0 = (lane & 48) | s0;         // stay within this quarter
            int r0 = __shfl(idx, src0);
            uint2 u0 = make_uint2(0u, 0u);
            if (s0 < m) u0 = *(const uint2*)(z8 + ((size_t)r0 << 6) + jj * 8);
            floatx2 p00 = __builtin_amdgcn_cvt_pk_f32_fp8(u0.x, false);
            floatx2 p01 = __builtin_amdgcn_cvt_pk_f32_fp8(u0.x, true);
            floatx2 p02 = __builtin_amdgcn_cvt_pk_f32_fp8(u0.y, false);
            floatx2 p03 = __builtin_amdgcn_cvt_pk_f32_fp8(u0.y, true);
            a[0] += p00.x;
            a[1] += p00.y;
            a[2] += p01.x;
            a[3] += p01.y;
            a[4] += p02.x;
            a[5] += p02.y;
            a[6] += p03.x;
            a[7] += p03.y;
        }
    }
    // merge the 2 edge slots within each 16-lane quarter
    #pragma unroll
    for (int q = 0; q < 8; ++q)
        a[q] += __shfl_xor(a[q], 8);
    if (ql < 8 && deg > 0) {
        float dn = rsqrtf((float)deg);           // == dis[node]
        float4* op = (float4*)(out + ((size_t)node << 6) + jj * 8);
        float4 o0 = op[0], o1 = op[1];
        o0.x += dn * a[0]; o0.y += dn * a[1]; o0.z += dn * a[2]; o0.w += dn * a[3];
        o1.x += dn * a[4]; o1.y += dn * a[5]; o1.z += dn * a[6]; o1.w += dn * a[7];
        op[0] = o0; op[1] = o1;
    }
}

extern "C" void kernel_launch(void* const* d_in, const int* in_sizes, int n_in,
                              void* d_out, int out_size, void* d_ws, size_t ws_size,
                              hipStream_t stream) {
    const float* x   = (const float*)d_in[0];
    const int*   ei  = (const int*)d_in[1];
    const float* W0  = (const float*)d_in[2];
    const float* W1  = (const float*)d_in[3];
    const float* W2  = (const float*)d_in[4];
    const float* Wfc = (const float*)d_in[5];
    float* out = (float*)d_out;
    int N = in_sizes[0] / N_IN;
    int E = in_sizes[1] / 2;
    int NBC = (N + CFB - 1) / CFB;        // 196
    int GB  = (N + 63) / 64;              // gemm tiles (782)
    int NFB = (E + CHUNK - 1) / CHUNK;    // fill parts (391) — must be <= NBC+GB

    __hip_bfloat16* CT = (__hip_bfloat16*)d_ws;             // 16384 bf16 = 32 KB
    int*   cnt     = (int*)((char*)d_ws + 32768);           // N
    float* dis     = (float*)(cnt + N);                     // N
    int*   gcur    = (int*)(dis + N);                       // NBC
    int*   fdone   = gcur + NBC;                            // 1 (+pad)
    int*   offs    = fdone + 64;                            // N
    unsigned* gsorted = (unsigned*)(offs + N);              // NBC*SLACKC
    unsigned short* srow = (unsigned short*)(gsorted + (size_t)NBC * SLACKC);
    size_t zoff = ((size_t)((char*)(srow + (size_t)NBC * SLACKC) - (char*)d_ws) + 63)
                  & ~(size_t)63;
    unsigned char* z8 = (unsigned char*)d_ws + zoff;        // N*64 fp8 (64B rows)
    size_t z16off = (zoff + (size_t)N * 64 + 63) & ~(size_t)63;
    __hip_bfloat16* z16 = (__hip_bfloat16*)((char*)d_ws + z16off);  // N*64 bf16

    prep_kernel<<<64, 256, 0, stream>>>(W0, W1, W2, Wfc, CT, gcur, fdone, NBC);
    fused_kernel<<<NBC + GB, 256, 0, stream>>>(ei, gcur, gsorted, srow, offs, cnt,
                                               dis, x, CT, out, z16, fdone,
                                               E, N, NBC, NFB);
    scale_kernel<<<(N * 8 + 255) / 256, 256, 0, stream>>>(z16, dis, z8, N);
    gather_kernel<<<(N + 15) / 16, 256, 0, stream>>>(offs, cnt, srow, z8, out, N);
}

// Round 11
// 133.909 us; speedup vs baseline: 1.8354x; 1.8354x over previous
//
#include <hip/hip_runtime.h>
#include <hip/hip_bf16.h>

#define N_IN  128
#define N_OUT 64
#define CFB    256          // nodes per coarse bucket (fill/sort granularity)
#define MAXNBC 200          // >= ceil(50000/256) = 196
#define SLACKC 5120         // slots per coarse bucket (mean 4096, +16 sigma)
#define CHUNK  3072         // edges per fill block (261 blocks -> all CUs busy)
#define PADR   136          // LDS row pitch in bf16 (+8 pad -> 2-way banks, free)

typedef __attribute__((ext_vector_type(8))) short short8;
typedef __attribute__((ext_vector_type(4))) float floatx4;
typedef __attribute__((ext_vector_type(2))) float floatx2;

__device__ __forceinline__ unsigned pack_bf16(float a, float b) {
    __hip_bfloat16 ba = __float2bfloat16(a);
    __hip_bfloat16 bb = __float2bfloat16(b);
    unsigned short ua = *(unsigned short*)&ba;
    unsigned short ub = *(unsigned short*)&bb;
    return ((unsigned)ub << 16) | ua;
}
__device__ __forceinline__ float bf16_to_f32(unsigned short u) {
    unsigned v = ((unsigned)u) << 16;
    return *(float*)&v;
}

// Append edges into per-coarse-bucket slack regions (relative cursors; gcur
// zeroed by memset). Runs average CHUNK/NBC ~ 16 edges -> writes still mostly
// cover cache lines. Blocks 0..63 also fold the weights into CT[128][128]
// bf16 (rows 0..63 = out cols; 64..127 = z cols) -- CT is only consumed by
// the NEXT dispatch, so overlapping it here is free.
__global__ __launch_bounds__(256) void fill_scatter(const int* __restrict__ ei,
                                                    int* __restrict__ gcur,
                                                    unsigned* __restrict__ gsorted,
                                                    const float* __restrict__ W0,
                                                    const float* __restrict__ W1,
                                                    const float* __restrict__ W2,
                                                    const float* __restrict__ Wfc,
                                                    __hip_bfloat16* __restrict__ CT,
                                                    int E, int NBC) {
    __shared__ int lcnt[MAXNBC];
    __shared__ int gbase_s[MAXNBC];
    int base = blockIdx.x * CHUNK;
    for (int i = threadIdx.x; i < NBC; i += 256) lcnt[i] = 0;
    __syncthreads();
    int myc[CHUNK / 256];
    #pragma unroll
    for (int q = 0; q < CHUNK / 256; ++q) {
        int e = base + q * 256 + threadIdx.x;
        int c = (e < E) ? ei[E + e] : -1;
        myc[q] = c;
        if (c >= 0) atomicAdd(&lcnt[c >> 8], 1);
    }
    __syncthreads();
    for (int f = threadIdx.x; f < NBC; f += 256) {
        int n = lcnt[f];
        gbase_s[f] = (n > 0) ? (f * SLACKC + atomicAdd(&gcur[f], n)) : 0;
    }
    __syncthreads();
    #pragma unroll
    for (int q = 0; q < CHUNK / 256; ++q) {
        int c = myc[q];
        if (c >= 0) {
            int e = base + q * 256 + threadIdx.x;
            unsigned r = (unsigned)ei[e];
            int p = atomicAdd(&gbase_s[c >> 8], 1);
            if (p < ((c >> 8) + 1) * SLACKC)   // overflow guard (P ~ 0)
                gsorted[p] = ((unsigned)c << 16) | r;
        }
    }
    // folded-weight compute (64 blocks x 256 threads = 16384 entries)
    if (blockIdx.x < 64) {
        int t = blockIdx.x * 256 + threadIdx.x;
        int n = t >> 7;
        int i = t & 127;
        float a = 0.f;
        if (n < 64) {
            for (int k = 0; k < 128; ++k)
                a += Wfc[n * 384 + k] * W0[k * N_IN + i];
        } else {
            int o = n - 64;
            for (int k = 0; k < 128; ++k)
                a += Wfc[o * 384 + 128 + k] * W1[k * N_IN + i]
                   + Wfc[o * 384 + 256 + k] * W2[k * N_IN + i];
        }
        CT[t] = __float2bfloat16(a);
    }
}

// Fused kernel. Blocks [0,NBC): per-coarse-bucket counting sort -> exact CSR
// (srow u16, offs/cnt/dis per node); edges staged in LDS; int LDS atomics only
// (f32 LDS atomicAdd is a CAS loop -- R5 lesson). Blocks [NBC,...): MFMA gemm
// out = x@C0^T, z16 = bf16(x@C12^T) UNSCALED (dis folded in by scale_kernel).
__global__ __launch_bounds__(256) void sortgemm_kernel(
        const int* __restrict__ gcur,
        const unsigned* __restrict__ gsorted,
        unsigned short* __restrict__ srow,
        int* __restrict__ offs,
        int* __restrict__ cnt,
        float* __restrict__ dis,
        const float* __restrict__ x,
        const __hip_bfloat16* __restrict__ CT,
        float* __restrict__ out,
        __hip_bfloat16* __restrict__ z16,
        int N, int NBC) {
    __shared__ __align__(16) char smem[(64 + 128) * PADR * 2];   // 52224 B union
    int tid = threadIdx.x;

    if (blockIdx.x < NBC) {
        // ---------------- sort partition ----------------
        unsigned* ev = (unsigned*)smem;               // up to SLACKC edges (20KB)
        int* c256 = (int*)(smem + SLACKC * 4);        // 256 counts
        int* cur  = c256 + 256;                       // 256 cursors
        int* ts   = cur + 256;                        // 256 scan temp
        int f = blockIdx.x;
        int lo = f * SLACKC;
        int m = min(gcur[f], SLACKC);                 // gcur is relative count
        for (int i = tid; i < m; i += 256) ev[i] = gsorted[lo + i];
        c256[tid] = 0;
        __syncthreads();
        for (int i = tid; i < m; i += 256)
            atomicAdd(&c256[(ev[i] >> 16) & (CFB - 1)], 1);
        __syncthreads();
        int v = c256[tid];
        int xx = v;
        ts[tid] = xx;
        __syncthreads();
        for (int off = 1; off < 256; off <<= 1) {
            int t2 = (tid >= off) ? ts[tid - off] : 0;
            __syncthreads();
            xx += t2; ts[tid] = xx;
            __syncthreads();
        }
        int b = xx - v;          // exclusive prefix
        cur[tid] = b;
        int node = f * CFB + tid;
        if (node < N) {
            offs[node] = lo + b;
            cnt[node] = v;
            dis[node] = v > 0 ? rsqrtf((float)v) : 0.f;
        }
        __syncthreads();
        for (int i = tid; i < m; i += 256) {
            unsigned val = ev[i];
            int cl = (val >> 16) & (CFB - 1);
            int p = atomicAdd(&cur[cl], 1);
            srow[lo + p] = (unsigned short)(val & 0xffffu);
        }
        return;
    }

    // ---------------- gemm partition ----------------
    unsigned short* xs = (unsigned short*)smem;          // 64 x PADR
    unsigned short* Bs = xs + 64 * PADR;                 // 128 x PADR
    int base = (blockIdx.x - NBC) * 64;

    {   // stage x -> bf16 LDS
        int row = tid >> 2;
        int colq = (tid & 3) * 32;
        int node = base + row;
        unsigned tmp[16];
        if (node < N) {
            const float4* src = (const float4*)(x + (size_t)node * N_IN + colq);
            #pragma unroll
            for (int q = 0; q < 8; ++q) {
                float4 v = src[q];
                tmp[q * 2]     = pack_bf16(v.x, v.y);
                tmp[q * 2 + 1] = pack_bf16(v.z, v.w);
            }
        } else {
            #pragma unroll
            for (int q = 0; q < 16; ++q) tmp[q] = 0u;
        }
        unsigned* dst = (unsigned*)(xs + row * PADR + colq);
        #pragma unroll
        for (int q = 0; q < 16; ++q) dst[q] = tmp[q];
    }
    {   // stage CT -> LDS
        const unsigned* src = (const unsigned*)CT;
        for (int c = tid; c < 8192; c += 256) {
            int row = c >> 6;
            int col = (c & 63) * 2;
            *(unsigned*)(Bs + row * PADR + col) = src[c];
        }
    }
    __syncthreads();

    int wave = tid >> 6, lane = tid & 63;
    int wm = wave & 1, wn = wave >> 1;
    int quad = lane >> 4, l16 = lane & 15;

    floatx4 acc[2][4];
    #pragma unroll
    for (int mt = 0; mt < 2; ++mt)
        #pragma unroll
        for (int nt = 0; nt < 4; ++nt)
            acc[mt][nt] = (floatx4){0.f, 0.f, 0.f, 0.f};

    #pragma unroll
    for (int kc = 0; kc < 4; ++kc) {
        int kof = kc * 32 + quad * 8;
        short8 afr[2], bfr[4];
        #pragma unroll
        for (int mt = 0; mt < 2; ++mt)
            afr[mt] = *(const short8*)(xs + (wm * 32 + mt * 16 + l16) * PADR + kof);
        #pragma unroll
        for (int nt = 0; nt < 4; ++nt)
            bfr[nt] = *(const short8*)(Bs + (wn * 64 + nt * 16 + l16) * PADR + kof);
        #pragma unroll
        for (int mt = 0; mt < 2; ++mt)
            #pragma unroll
            for (int nt = 0; nt < 4; ++nt)
                acc[mt][nt] = __builtin_amdgcn_mfma_f32_16x16x32_bf16(
                    afr[mt], bfr[nt], acc[mt][nt], 0, 0, 0);
    }

    #pragma unroll
    for (int mt = 0; mt < 2; ++mt) {
        #pragma unroll
        for (int reg = 0; reg < 4; ++reg) {
            int node = base + wm * 32 + mt * 16 + quad * 4 + reg;
            if (node >= N) continue;
            if (wn == 0) {
                #pragma unroll
                for (int nt = 0; nt < 4; ++nt)
                    out[(size_t)node * N_OUT + nt * 16 + l16] = acc[mt][nt][reg];
            } else {
                #pragma unroll
                for (int nt = 0; nt < 4; ++nt)
                    z16[((size_t)node << 6) + nt * 16 + l16] =
                        __float2bfloat16(acc[mt][nt][reg]);
            }
        }
    }
}

// z8[node][d] = fp8( dis[node] * z16[node][d] ).  Streams ~10 MB; removes the
// per-edge random dis[idx] load from gather (validated: absmax identical).
__global__ __launch_bounds__(256) void scale_kernel(
        const __hip_bfloat16* __restrict__ z16,
        const float* __restrict__ dis,
        unsigned char* __restrict__ z8,
        int N) {
    int t = blockIdx.x * 256 + threadIdx.x;   // one thread = 8 dims
    if (t >= N * 8) return;
    int node = t >> 3;
    float d = dis[node];
    short8 v = *(const short8*)((const unsigned short*)z16 + (size_t)t * 8);
    float f[8];
    #pragma unroll
    for (int j = 0; j < 8; ++j)
        f[j] = bf16_to_f32((unsigned short)v[j]) * d;
    unsigned lo = 0, hi = 0;
    lo = __builtin_amdgcn_cvt_pk_fp8_f32(f[0], f[1], lo, false);
    lo = __builtin_amdgcn_cvt_pk_fp8_f32(f[2], f[3], lo, true);
    hi = __builtin_amdgcn_cvt_pk_fp8_f32(f[4], f[5], hi, false);
    hi = __builtin_amdgcn_cvt_pk_fp8_f32(f[6], f[7], hi, true);
    uint2 o; o.x = lo; o.y = hi;
    *(uint2*)(z8 + (size_t)t * 8) = o;
}

// FOUR nodes per wave (16 lanes each: 2 edge-slots x 8 dim-lanes), register
// acc, no atomics. z8 rows are PRE-SCALED by dis[row]: per edge = 1 shfl +
// one 8B random load + 8 adds (no dis gather, no dv shfl).
__global__ __launch_bounds__(256) void gather_kernel(
        const int* __restrict__ offs, const int* __restrict__ cnt,
        const unsigned short* __restrict__ srow, const unsigned char* __restrict__ z8,
        float* __restrict__ out, int N) {
    int lane = threadIdx.x & 63;
    int quarter = lane >> 4;     // which node of the four
    int ql   = lane & 15;        // lane within quarter
    int sub  = ql >> 3;          // edge slot 0..1
    int jj   = ql & 7;           // byte-chunk: dims 8jj..8jj+7
    int node = blockIdx.x * 16 + (threadIdx.x >> 6) * 4 + quarter;
    int start = 0, deg = 0;
    if (node < N) { start = offs[node]; deg = cnt[node]; }
    float a[8] = {0.f, 0.f, 0.f, 0.f, 0.f, 0.f, 0.f, 0.f};
    for (int k0 = 0; k0 < deg; k0 += 16) {
        int m = min(16, deg - k0);               // per-quarter edge count
        int idx = 0;
        if (ql < m)
            idx = (int)srow[start + k0 + ql];    // coalesced u16, all quarters at once
        #pragma unroll
        for (int it = 0; it < 8; ++it) {
            int s0 = it * 2 + sub;
            int src0 = (lane & 48) | s0;         // stay within this quarter
            int r0 = __shfl(idx, src0);
            uint2 u0 = make_uint2(0u, 0u);
            if (s0 < m) u0 = *(const uint2*)(z8 + ((size_t)r0 << 6) + jj * 8);
            floatx2 p00 = __builtin_amdgcn_cvt_pk_f32_fp8(u0.x, false);
            floatx2 p01 = __builtin_amdgcn_cvt_pk_f32_fp8(u0.x, true);
            floatx2 p02 = __builtin_amdgcn_cvt_pk_f32_fp8(u0.y, false);
            floatx2 p03 = __builtin_amdgcn_cvt_pk_f32_fp8(u0.y, true);
            a[0] += p00.x;
            a[1] += p00.y;
            a[2] += p01.x;
            a[3] += p01.y;
            a[4] += p02.x;
            a[5] += p02.y;
            a[6] += p03.x;
            a[7] += p03.y;
        }
    }
    // merge the 2 edge slots within each 16-lane quarter
    #pragma unroll
    for (int q = 0; q < 8; ++q)
        a[q] += __shfl_xor(a[q], 8);
    if (ql < 8 && deg > 0) {
        float dn = rsqrtf((float)deg);           // == dis[node]
        float4* op = (float4*)(out + ((size_t)node << 6) + jj * 8);
        float4 o0 = op[0], o1 = op[1];
        o0.x += dn * a[0]; o0.y += dn * a[1]; o0.z += dn * a[2]; o0.w += dn * a[3];
        o1.x += dn * a[4]; o1.y += dn * a[5]; o1.z += dn * a[6]; o1.w += dn * a[7];
        op[0] = o0; op[1] = o1;
    }
}

extern "C" void kernel_launch(void* const* d_in, const int* in_sizes, int n_in,
                              void* d_out, int out_size, void* d_ws, size_t ws_size,
                              hipStream_t stream) {
    const float* x   = (const float*)d_in[0];
    const int*   ei  = (const int*)d_in[1];
    const float* W0  = (const float*)d_in[2];
    const float* W1  = (const float*)d_in[3];
    const float* W2  = (const float*)d_in[4];
    const float* Wfc = (const float*)d_in[5];
    float* out = (float*)d_out;
    int N = in_sizes[0] / N_IN;
    int E = in_sizes[1] / 2;
    int NBC = (N + CFB - 1) / CFB;   // 196
    int GB  = (N + 63) / 64;         // gemm blocks (782)

    __hip_bfloat16* CT = (__hip_bfloat16*)d_ws;             // 16384 bf16 = 32 KB
    int*   cnt     = (int*)((char*)d_ws + 32768);           // N
    float* dis     = (float*)(cnt + N);                     // N
    int*   gcur    = (int*)(dis + N);                       // NBC (zeroed)
    int*   offs    = gcur + NBC;                            // N
    unsigned* gsorted = (unsigned*)(offs + N);              // NBC*SLACKC
    unsigned short* srow = (unsigned short*)(gsorted + (size_t)NBC * SLACKC);
    size_t zoff = ((size_t)((char*)(srow + (size_t)NBC * SLACKC) - (char*)d_ws) + 63)
                  & ~(size_t)63;
    unsigned char* z8 = (unsigned char*)d_ws + zoff;        // N*64 fp8 (64B rows)
    size_t z16off = (zoff + (size_t)N * 64 + 63) & ~(size_t)63;
    __hip_bfloat16* z16 = (__hip_bfloat16*)((char*)d_ws + z16off);  // N*64 bf16

    hipMemsetAsync(gcur, 0, (size_t)NBC * sizeof(int), stream);
    fill_scatter<<<(E + CHUNK - 1) / CHUNK, 256, 0, stream>>>(ei, gcur, gsorted,
                                                              W0, W1, W2, Wfc, CT, E, NBC);
    sortgemm_kernel<<<NBC + GB, 256, 0, stream>>>(gcur, gsorted, srow, offs, cnt, dis,
                                                  x, CT, out, z16, N, NBC);
    scale_kernel<<<(N * 8 + 255) / 256, 256, 0, stream>>>(z16, dis, z8, N);
    gather_kernel<<<(N + 15) / 16, 256, 0, stream>>>(offs, cnt, srow, z8, out, N);
}

// Round 15
// 131.498 us; speedup vs baseline: 1.8691x; 1.0183x over previous
//
#include <hip/hip_runtime.h>
#include <hip/hip_bf16.h>

#define N_IN  128
#define N_OUT 64
#define CFB    256          // nodes per coarse bucket (sort granularity)
#define MAXNBC 200          // >= ceil(50000/256) = 196
#define SLACKC 5120         // slots per coarse bucket (mean 4096, +16 sigma)
#define CHUNK  3072         // edges per fill part (261 parts)
#define PADR   136          // LDS row pitch in bf16 (+8 pad -> 2-way banks, free)

typedef __attribute__((ext_vector_type(8))) short short8;
typedef __attribute__((ext_vector_type(4))) float floatx4;
typedef __attribute__((ext_vector_type(2))) float floatx2;

__device__ __forceinline__ unsigned pack_bf16(float a, float b) {
    __hip_bfloat16 ba = __float2bfloat16(a);
    __hip_bfloat16 bb = __float2bfloat16(b);
    unsigned short ua = *(unsigned short*)&ba;
    unsigned short ub = *(unsigned short*)&bb;
    return ((unsigned)ub << 16) | ua;
}
__device__ __forceinline__ float bf16_to_f32(unsigned short u) {
    unsigned v = ((unsigned)u) << 16;
    return *(float*)&v;
}

// D1: fold weights into CT[128][128] bf16 (rows 0..63 = out cols, 64..127 =
// z cols); block 0 also zeroes gcur (replaces the hipMemsetAsync dispatch).
// Numerics identical to the R2-validated prep.
__global__ __launch_bounds__(256) void prep_kernel(const float* __restrict__ W0,
                                                   const float* __restrict__ W1,
                                                   const float* __restrict__ W2,
                                                   const float* __restrict__ Wfc,
                                                   __hip_bfloat16* __restrict__ CT,
                                                   int* __restrict__ gcur,
                                                   int NBC) {
    if (blockIdx.x == 0) {
        for (int i = threadIdx.x; i < NBC; i += 256) gcur[i] = 0;
    }
    int t = blockIdx.x * 256 + threadIdx.x;   // 0..16383
    int n = t >> 7;
    int i = t & 127;
    float a = 0.f;
    if (n < 64) {
        #pragma unroll 4
        for (int k = 0; k < 128; ++k)
            a += Wfc[n * 384 + k] * W0[k * N_IN + i];
    } else {
        int o = n - 64;
        #pragma unroll 4
        for (int k = 0; k < 128; ++k)
            a += Wfc[o * 384 + 128 + k] * W1[k * N_IN + i]
               + Wfc[o * 384 + 256 + k] * W2[k * N_IN + i];
    }
    CT[t] = __float2bfloat16(a);
}

// D2: fill ∥ gemm in ONE dispatch.  The two partitions are fully independent
// (fill touches ei/gcur/gsorted; gemm touches x/CT/out/z16) -- no spin, no
// fence, no cross-block wait (the R2 lesson: spin barriers serialize the
// grid; independence is free).  Fill's serial prologue time hides under gemm.
__global__ __launch_bounds__(256) void fillgemm_kernel(
        const int* __restrict__ ei,
        int* __restrict__ gcur,
        unsigned* __restrict__ gsorted,
        const float* __restrict__ x,
        const __hip_bfloat16* __restrict__ CT,
        float* __restrict__ out,
        __hip_bfloat16* __restrict__ z16,
        int E, int N, int NFB) {
    __shared__ __align__(16) char smem[(64 + 128) * PADR * 2];   // 52224 B union
    int tid = threadIdx.x;
    int bid = blockIdx.x;

    if (bid < NFB) {
        // ---------------- fill partition ----------------
        int* lcnt = (int*)smem;
        int* gbase_s = lcnt + MAXNBC;
        int base = bid * CHUNK;
        for (int i = tid; i < MAXNBC; i += 256) lcnt[i] = 0;
        __syncthreads();
        int myc[CHUNK / 256];
        #pragma unroll
        for (int q = 0; q < CHUNK / 256; ++q) {
            int e = base + q * 256 + tid;
            int c = (e < E) ? ei[E + e] : -1;
            myc[q] = c;
            if (c >= 0) atomicAdd(&lcnt[c >> 8], 1);
        }
        __syncthreads();
        for (int f = tid; f < MAXNBC; f += 256) {
            int n = lcnt[f];
            gbase_s[f] = (n > 0) ? (f * SLACKC + atomicAdd(&gcur[f], n)) : 0;
        }
        __syncthreads();
        #pragma unroll
        for (int q = 0; q < CHUNK / 256; ++q) {
            int c = myc[q];
            if (c >= 0) {
                int e = base + q * 256 + tid;
                unsigned r = (unsigned)ei[e];
                int p = atomicAdd(&gbase_s[c >> 8], 1);
                if (p < ((c >> 8) + 1) * SLACKC)   // overflow guard (P ~ 0)
                    gsorted[p] = ((unsigned)c << 16) | r;
            }
        }
        return;
    }

    // ---------------- gemm partition ----------------
    unsigned short* xs = (unsigned short*)smem;          // 64 x PADR
    unsigned short* Bs = xs + 64 * PADR;                 // 128 x PADR
    int base = (bid - NFB) * 64;

    {   // stage x -> bf16 LDS
        int row = tid >> 2;
        int colq = (tid & 3) * 32;
        int node = base + row;
        unsigned tmp[16];
        if (node < N) {
            const float4* src = (const float4*)(x + (size_t)node * N_IN + colq);
            #pragma unroll
            for (int q = 0; q < 8; ++q) {
                float4 v = src[q];
                tmp[q * 2]     = pack_bf16(v.x, v.y);
                tmp[q * 2 + 1] = pack_bf16(v.z, v.w);
            }
        } else {
            #pragma unroll
            for (int q = 0; q < 16; ++q) tmp[q] = 0u;
        }
        unsigned* dst = (unsigned*)(xs + row * PADR + colq);
        #pragma unroll
        for (int q = 0; q < 16; ++q) dst[q] = tmp[q];
    }
    {   // stage CT -> LDS
        const unsigned* src = (const unsigned*)CT;
        for (int c = tid; c < 8192; c += 256) {
            int row = c >> 6;
            int col = (c & 63) * 2;
            *(unsigned*)(Bs + row * PADR + col) = src[c];
        }
    }
    __syncthreads();

    int wave = tid >> 6, lane = tid & 63;
    int wm = wave & 1, wn = wave >> 1;
    int quad = lane >> 4, l16 = lane & 15;

    floatx4 acc[2][4];
    #pragma unroll
    for (int mt = 0; mt < 2; ++mt)
        #pragma unroll
        for (int nt = 0; nt < 4; ++nt)
            acc[mt][nt] = (floatx4){0.f, 0.f, 0.f, 0.f};

    #pragma unroll
    for (int kc = 0; kc < 4; ++kc) {
        int kof = kc * 32 + quad * 8;
        short8 afr[2], bfr[4];
        #pragma unroll
        for (int mt = 0; mt < 2; ++mt)
            afr[mt] = *(const short8*)(xs + (wm * 32 + mt * 16 + l16) * PADR + kof);
        #pragma unroll
        for (int nt = 0; nt < 4; ++nt)
            bfr[nt] = *(const short8*)(Bs + (wn * 64 + nt * 16 + l16) * PADR + kof);
        #pragma unroll
        for (int mt = 0; mt < 2; ++mt)
            #pragma unroll
            for (int nt = 0; nt < 4; ++nt)
                acc[mt][nt] = __builtin_amdgcn_mfma_f32_16x16x32_bf16(
                    afr[mt], bfr[nt], acc[mt][nt], 0, 0, 0);
    }

    #pragma unroll
    for (int mt = 0; mt < 2; ++mt) {
        #pragma unroll
        for (int reg = 0; reg < 4; ++reg) {
            int node = base + wm * 32 + mt * 16 + quad * 4 + reg;
            if (node >= N) continue;
            if (wn == 0) {
                #pragma unroll
                for (int nt = 0; nt < 4; ++nt)
                    out[(size_t)node * N_OUT + nt * 16 + l16] = acc[mt][nt][reg];
            } else {
                #pragma unroll
                for (int nt = 0; nt < 4; ++nt)
                    z16[((size_t)node << 6) + nt * 16 + l16] =
                        __float2bfloat16(acc[mt][nt][reg]);
            }
        }
    }
}

// D3: per-coarse-bucket counting sort -> exact CSR (srow u16, offs/cnt/dis).
// Identical to the verified sort partition.
__global__ __launch_bounds__(256) void sort_kernel(
        const int* __restrict__ gcur,
        const unsigned* __restrict__ gsorted,
        unsigned short* __restrict__ srow,
        int* __restrict__ offs,
        int* __restrict__ cnt,
        float* __restrict__ dis,
        int N) {
    __shared__ __align__(16) char smem[SLACKC * 4 + 3 * 256 * 4];
    int tid = threadIdx.x;
    unsigned* ev = (unsigned*)smem;               // up to SLACKC edges (20KB)
    int* c256 = (int*)(smem + SLACKC * 4);        // 256 counts
    int* cur  = c256 + 256;                       // 256 cursors
    int* ts   = cur + 256;                        // 256 scan temp
    int f = blockIdx.x;
    int lo = f * SLACKC;
    int m = min(gcur[f], SLACKC);                 // gcur is relative count
    for (int i = tid; i < m; i += 256) ev[i] = gsorted[lo + i];
    c256[tid] = 0;
    __syncthreads();
    for (int i = tid; i < m; i += 256)
        atomicAdd(&c256[(ev[i] >> 16) & (CFB - 1)], 1);
    __syncthreads();
    int v = c256[tid];
    int xx = v;
    ts[tid] = xx;
    __syncthreads();
    for (int off = 1; off < 256; off <<= 1) {
        int t2 = (tid >= off) ? ts[tid - off] : 0;
        __syncthreads();
        xx += t2; ts[tid] = xx;
        __syncthreads();
    }
    int b = xx - v;          // exclusive prefix
    cur[tid] = b;
    int node = f * CFB + tid;
    if (node < N) {
        offs[node] = lo + b;
        cnt[node] = v;
        dis[node] = v > 0 ? rsqrtf((float)v) : 0.f;
    }
    __syncthreads();
    for (int i = tid; i < m; i += 256) {
        unsigned val = ev[i];
        int cl = (val >> 16) & (CFB - 1);
        int p = atomicAdd(&cur[cl], 1);
        srow[lo + p] = (unsigned short)(val & 0xffffu);
    }
}

// D4: z8[node][d] = fp8( dis[node] * z16[node][d] ).  ~10 MB streamed.
__global__ __launch_bounds__(256) void scale_kernel(
        const __hip_bfloat16* __restrict__ z16,
        const float* __restrict__ dis,
        unsigned char* __restrict__ z8,
        int N) {
    int t = blockIdx.x * 256 + threadIdx.x;   // one thread = 8 dims
    if (t >= N * 8) return;
    int node = t >> 3;
    float d = dis[node];
    short8 v = *(const short8*)((const unsigned short*)z16 + (size_t)t * 8);
    float f[8];
    #pragma unroll
    for (int j = 0; j < 8; ++j)
        f[j] = bf16_to_f32((unsigned short)v[j]) * d;
    unsigned lo = 0, hi = 0;
    lo = __builtin_amdgcn_cvt_pk_fp8_f32(f[0], f[1], lo, false);
    lo = __builtin_amdgcn_cvt_pk_fp8_f32(f[2], f[3], lo, true);
    hi = __builtin_amdgcn_cvt_pk_fp8_f32(f[4], f[5], hi, false);
    hi = __builtin_amdgcn_cvt_pk_fp8_f32(f[6], f[7], hi, true);
    uint2 o; o.x = lo; o.y = hi;
    *(uint2*)(z8 + (size_t)t * 8) = o;
}

// D5: gather.  Pre-scaled z8 -> per edge = 1 shfl + one 8B random load +
// 4 packed f32x2 adds (v_pk_add_f32) -- same values/order as the scalar
// form, ~30% fewer VALU inst per edge.
__global__ __launch_bounds__(256) void gather_kernel(
        const int* __restrict__ offs, const int* __restrict__ cnt,
        const unsigned short* __restrict__ srow, const unsigned char* __restrict__ z8,
        float* __restrict__ out, int N) {
    int lane = threadIdx.x & 63;
    int quarter = lane >> 4;     // which node of the four
    int ql   = lane & 15;        // lane within quarter
    int sub  = ql >> 3;          // edge slot 0..1
    int jj   = ql & 7;           // byte-chunk: dims 8jj..8jj+7
    int node = blockIdx.x * 16 + (threadIdx.x >> 6) * 4 + quarter;
    int start = 0, deg = 0;
    if (node < N) { start = offs[node]; deg = cnt[node]; }
    floatx2 a2[4];
    #pragma unroll
    for (int q = 0; q < 4; ++q) a2[q] = (floatx2){0.f, 0.f};
    for (int k0 = 0; k0 < deg; k0 += 16) {
        int m = min(16, deg - k0);               // per-quarter edge count
        int idx = 0;
        if (ql < m)
            idx = (int)srow[start + k0 + ql];    // coalesced u16, all quarters at once
        #pragma unroll
        for (int it = 0; it < 8; ++it) {
            int s0 = it * 2 + sub;
            int src0 = (lane & 48) | s0;         // stay within this quarter
            int r0 = __shfl(idx, src0);
            uint2 u0 = make_uint2(0u, 0u);
            if (s0 < m) u0 = *(const uint2*)(z8 + ((size_t)r0 << 6) + jj * 8);
            a2[0] += __builtin_amdgcn_cvt_pk_f32_fp8(u0.x, false);
            a2[1] += __builtin_amdgcn_cvt_pk_f32_fp8(u0.x, true);
            a2[2] += __builtin_amdgcn_cvt_pk_f32_fp8(u0.y, false);
            a2[3] += __builtin_amdgcn_cvt_pk_f32_fp8(u0.y, true);
        }
    }
    // merge the 2 edge slots within each 16-lane quarter
    #pragma unroll
    for (int q = 0; q < 4; ++q) {
        a2[q].x += __shfl_xor(a2[q].x, 8);
        a2[q].y += __shfl_xor(a2[q].y, 8);
    }
    if (ql < 8 && deg > 0) {
        float dn = rsqrtf((float)deg);           // == dis[node]
        float4* op = (float4*)(out + ((size_t)node << 6) + jj * 8);
        float4 o0 = op[0], o1 = op[1];
        o0.x += dn * a2[0].x; o0.y += dn * a2[0].y;
        o0.z += dn * a2[1].x; o0.w += dn * a2[1].y;
        o1.x += dn * a2[2].x; o1.y += dn * a2[2].y;
        o1.z += dn * a2[3].x; o1.w += dn * a2[3].y;
        op[0] = o0; op[1] = o1;
    }
}

extern "C" void kernel_launch(void* const* d_in, const int* in_sizes, int n_in,
                              void* d_out, int out_size, void* d_ws, size_t ws_size,
                              hipStream_t stream) {
    const float* x   = (const float*)d_in[0];
    const int*   ei  = (const int*)d_in[1];
    const float* W0  = (const float*)d_in[2];
    const float* W1  = (const float*)d_in[3];
    const float* W2  = (const float*)d_in[4];
    const float* Wfc = (const float*)d_in[5];
    float* out = (float*)d_out;
    int N = in_sizes[0] / N_IN;
    int E = in_sizes[1] / 2;
    int NBC = (N + CFB - 1) / CFB;        // 196
    int GB  = (N + 63) / 64;              // gemm tiles (782)
    int NFB = (E + CHUNK - 1) / CHUNK;    // fill parts (261)

    __hip_bfloat16* CT = (__hip_bfloat16*)d_ws;             // 16384 bf16 = 32 KB
    int*   cnt     = (int*)((char*)d_ws + 32768);           // N
    float* dis     = (float*)(cnt + N);                     // N
    int*   gcur    = (int*)(dis + N);                       // NBC (zeroed by prep)
    int*   offs    = gcur + NBC;                            // N
    unsigned* gsorted = (unsigned*)(offs + N);              // NBC*SLACKC
    unsigned short* srow = (unsigned short*)(gsorted + (size_t)NBC * SLACKC);
    size_t zoff = ((size_t)((char*)(srow + (size_t)NBC * SLACKC) - (char*)d_ws) + 63)
                  & ~(size_t)63;
    unsigned char* z8 = (unsigned char*)d_ws + zoff;        // N*64 fp8 (64B rows)
    size_t z16off = (zoff + (size_t)N * 64 + 63) & ~(size_t)63;
    __hip_bfloat16* z16 = (__hip_bfloat16*)((char*)d_ws + z16off);  // N*64 bf16

    prep_kernel<<<64, 256, 0, stream>>>(W0, W1, W2, Wfc, CT, gcur, NBC);
    fillgemm_kernel<<<NFB + GB, 256, 0, stream>>>(ei, gcur, gsorted, x, CT,
                                                  out, z16, E, N, NFB);
    sort_kernel<<<NBC, 256, 0, stream>>>(gcur, gsorted, srow, offs, cnt, dis, N);
    scale_kernel<<<(N * 8 + 255) / 256, 256, 0, stream>>>(z16, dis, z8, N);
    gather_kernel<<<(N + 15) / 16, 256, 0, stream>>>(offs, cnt, srow, z8, out, N);
}